// Round 7
// baseline (347.401 us; speedup 1.0000x reference)
//
#include <hip/hip_runtime.h>

typedef __bf16 bf16x8 __attribute__((ext_vector_type(8)));
typedef float f32x4 __attribute__((ext_vector_type(4)));
typedef _Float16 h4 __attribute__((ext_vector_type(4)));
typedef unsigned short u16;

#define ASYNC16(gp, lp) __builtin_amdgcn_global_load_lds( \
    (__attribute__((address_space(1))) void*)(gp),        \
    (__attribute__((address_space(3))) void*)(lp), 16, 0, 0)

// ---------------- helpers ----------------
static __device__ __forceinline__ u16 f2bf(float f) {
    union { float f; unsigned u; } v; v.f = f;
    unsigned r = v.u + 0x7FFFu + ((v.u >> 16) & 1u);   // RNE
    return (u16)(r >> 16);
}
static __device__ __forceinline__ u16 f2h(float f) {
    _Float16 h = (_Float16)f;
    union { _Float16 h; u16 u; } c; c.h = h;
    return c.u;
}

#define QSCALE 0.18033688011112042f  /* 0.125 * log2(e) */

// ---------------- convert / transpose ----------------
__global__ void transpose_convert(const float* __restrict__ in, u16* __restrict__ out,
                                  int K, int N) {
    __shared__ float tile[32][33];
    int n0 = blockIdx.x * 32, k0 = blockIdx.y * 32;
    int tx = threadIdx.x, ty = threadIdx.y;
    for (int i = 0; i < 4; i++)
        tile[ty + 8 * i][tx] = in[(size_t)(k0 + ty + 8 * i) * N + n0 + tx];
    __syncthreads();
    for (int i = 0; i < 4; i++)
        out[(size_t)(n0 + ty + 8 * i) * K + k0 + tx] = f2bf(tile[tx][ty + 8 * i]);
}

__global__ void convert_bf16(const float* __restrict__ in, u16* __restrict__ out) {
    size_t i = ((size_t)blockIdx.x * 256 + threadIdx.x) * 4;
    float4 v = *(const float4*)&in[i];
    u16 o0 = f2bf(v.x), o1 = f2bf(v.y), o2 = f2bf(v.z), o3 = f2bf(v.w);
    ushort4 o; o.x = o0; o.y = o1; o.z = o2; o.w = o3;
    *(ushort4*)&out[i] = o;
}

// V [bh][t][d] -> VT [bh][d][t]   grid(32, 32) block(64,8)  (u16 passthrough)
__global__ void vtrans_kernel(const u16* __restrict__ Vp, u16* __restrict__ VT) {
    __shared__ u16 tile[64 * 66];
    const int bh = blockIdx.y, t0 = blockIdx.x * 64;
    const int tx = threadIdx.x, ty = threadIdx.y;
    const u16* src = Vp + (size_t)bh * 2048 * 64;
    u16* dst = VT + (size_t)bh * 64 * 2048;
    for (int i = 0; i < 8; i++)
        tile[(ty + 8 * i) * 66 + tx] = src[(size_t)(t0 + ty + 8 * i) * 64 + tx];
    __syncthreads();
    for (int i = 0; i < 8; i++) {
        int d = ty + 8 * i;
        dst[(size_t)d * 2048 + t0 + tx] = tile[tx * 66 + d];
    }
}

// ---------------- GEMM 128x128, single-barrier double-buffered pipeline ----------
// EPI 0: scatter to Q/K (bf16) + V (f16) [B,H,T,D]; Q scaled by QSCALE
// EPI 1: fp32 out = acc + bias + resid[m*N+n]
// EPI 2: bf16 out = relu(acc + bias)
template <int EPI>
__global__ __launch_bounds__(256) void gemm_kernel(
    const u16* __restrict__ A, const u16* __restrict__ BT,
    const float* __restrict__ bias, void* __restrict__ out0,
    const float* __restrict__ resid, int M, int N, int K,
    u16* __restrict__ q_out, u16* __restrict__ k_out, u16* __restrict__ v_out)
{
    __shared__ __align__(16) u16 As[2][128 * 32];
    __shared__ __align__(16) u16 Bs[2][128 * 32];
    const int tid = threadIdx.x;
    const int wave = tid >> 6, lane = tid & 63;
    const int quad = lane >> 4, l16 = lane & 15;
    const int m0 = blockIdx.y * 128, n0 = blockIdx.x * 128;
    const int wm = (wave >> 1) * 64, wn = (wave & 1) * 64;
    const int sr = tid >> 2, sc = (tid & 3) * 8;

    f32x4 acc[4][4] = {};

#define GISSUE(k0v, bb) do {                                                         \
        ASYNC16(&A[(size_t)(m0 + sr) * K + (k0v) + sc],       &As[bb][sr * 32 + sc]);        \
        ASYNC16(&A[(size_t)(m0 + sr + 64) * K + (k0v) + sc],  &As[bb][(sr + 64) * 32 + sc]); \
        ASYNC16(&BT[(size_t)(n0 + sr) * K + (k0v) + sc],      &Bs[bb][sr * 32 + sc]);        \
        ASYNC16(&BT[(size_t)(n0 + sr + 64) * K + (k0v) + sc], &Bs[bb][(sr + 64) * 32 + sc]); \
    } while (0)

    const int nk = K >> 5;
    GISSUE(0, 0);
    for (int it = 0; it < nk; it++) {
        __syncthreads();
        if (it + 1 < nk) GISSUE((it + 1) * 32, (it + 1) & 1);
        const u16* Ab = As[it & 1];
        const u16* Bb = Bs[it & 1];
        bf16x8 af[4], bfr[4];
        for (int i = 0; i < 4; i++) {
            af[i]  = *(const bf16x8*)&Ab[(wm + i * 16 + l16) * 32 + quad * 8];
            bfr[i] = *(const bf16x8*)&Bb[(wn + i * 16 + l16) * 32 + quad * 8];
        }
        for (int i = 0; i < 4; i++)
            for (int j = 0; j < 4; j++)
                acc[i][j] = __builtin_amdgcn_mfma_f32_16x16x32_bf16(af[i], bfr[j], acc[i][j], 0, 0, 0);
    }
#undef GISSUE

    for (int i = 0; i < 4; i++) {
        int mbase = m0 + wm + i * 16 + quad * 4;
        for (int j = 0; j < 4; j++) {
            int n = n0 + wn + j * 16 + l16;
            float bv = bias[n];
            for (int r = 0; r < 4; r++) {
                int m = mbase + r;
                float v = acc[i][j][r] + bv;
                if (EPI == 0) {
                    int s = n >> 10, rr = n & 1023, h = rr >> 6, d = rr & 63;
                    int b = m >> 11, t = m & 2047;
                    if (s == 0) v *= QSCALE;
                    u16* dst = (s == 0) ? q_out : (s == 1) ? k_out : v_out;
                    u16 bits = (s == 2) ? f2h(v) : f2bf(v);
                    dst[((size_t)((b * 16 + h) * 2048 + t)) * 64 + d] = bits;
                } else if (EPI == 1) {
                    ((float*)out0)[(size_t)m * N + n] = v + resid[(size_t)m * N + n];
                } else {
                    ((u16*)out0)[(size_t)m * N + n] = f2bf(fmaxf(v, 0.f));
                }
            }
        }
    }
}

// ---------------- GEMM 64x128 (N=1024 GEMMs: 512 blocks => 2/CU) -----------
__global__ __launch_bounds__(256) void gemm64_kernel(
    const u16* __restrict__ A, const u16* __restrict__ BT,
    const float* __restrict__ bias, float* __restrict__ out0,
    const float* __restrict__ resid, int M, int N, int K)
{
    __shared__ __align__(16) u16 As[2][64 * 32];
    __shared__ __align__(16) u16 Bs[2][128 * 32];
    const int tid = threadIdx.x;
    const int wave = tid >> 6, lane = tid & 63;
    const int quad = lane >> 4, l16 = lane & 15;
    const int m0 = blockIdx.y * 64, n0 = blockIdx.x * 128;
    const int wn = wave * 32;
    const int sr = tid >> 2, sc = (tid & 3) * 8;

    f32x4 acc[4][2] = {};

#define GISSUE(k0v, bb) do {                                                         \
        ASYNC16(&A[(size_t)(m0 + sr) * K + (k0v) + sc],       &As[bb][sr * 32 + sc]);        \
        ASYNC16(&BT[(size_t)(n0 + sr) * K + (k0v) + sc],      &Bs[bb][sr * 32 + sc]);        \
        ASYNC16(&BT[(size_t)(n0 + sr + 64) * K + (k0v) + sc], &Bs[bb][(sr + 64) * 32 + sc]); \
    } while (0)

    const int nk = K >> 5;
    GISSUE(0, 0);
    for (int it = 0; it < nk; it++) {
        __syncthreads();
        if (it + 1 < nk) GISSUE((it + 1) * 32, (it + 1) & 1);
        const u16* Ab = As[it & 1];
        const u16* Bb = Bs[it & 1];
        bf16x8 af[4], bfr[2];
        for (int i = 0; i < 4; i++)
            af[i] = *(const bf16x8*)&Ab[(i * 16 + l16) * 32 + quad * 8];
        for (int j = 0; j < 2; j++)
            bfr[j] = *(const bf16x8*)&Bb[(wn + j * 16 + l16) * 32 + quad * 8];
        for (int i = 0; i < 4; i++)
            for (int j = 0; j < 2; j++)
                acc[i][j] = __builtin_amdgcn_mfma_f32_16x16x32_bf16(af[i], bfr[j], acc[i][j], 0, 0, 0);
    }
#undef GISSUE

    for (int i = 0; i < 4; i++) {
        int mbase = m0 + i * 16 + quad * 4;
        for (int j = 0; j < 2; j++) {
            int n = n0 + wn + j * 16 + l16;
            float bv = bias[n];
            for (int r = 0; r < 4; r++) {
                int m = mbase + r;
                out0[(size_t)m * N + n] = acc[i][j][r] + bv + resid[(size_t)m * N + n];
            }
        }
    }
}

// ---------------- flash attention v6: no P-relayout ----------------
// S^T = K*Q^T (swapped MFMA operands, same register data): C-layout gives
// lane l16 = q, reg r -> t = quad*4+r, which IS the A-operand layout of the
// K=16 MFMA. P goes exp2 -> f16 pack -> v_mfma_f32_16x16x16f16 in-register.
// V stored as f16; V B-frags = contiguous ds_read_b64 from Vs.
// Grid = 1024 single 64-row Q-tile blocks, heavy tiles first; 4 blocks/CU.
__global__ __launch_bounds__(256) void attn_kernel(
    const u16* __restrict__ Qp, const u16* __restrict__ Kp,
    const u16* __restrict__ VTg, u16* __restrict__ Hb)
{
    __shared__ __align__(16) u16 Ks[2][2][64][32];   // [buf][d-panel][t][d]
    __shared__ __align__(16) u16 Vs[2][2][64][32];   // [buf][t-panel][d][t]  (f16 bits)
    const int tid = threadIdx.x;
    const int wave = tid >> 6, lane = tid & 63;
    const int quad = lane >> 4, l16 = lane & 15;
    const int bh = ((blockIdx.x & 7) << 2) | ((blockIdx.x >> 3) & 3);
    const int qt = 31 - (blockIdx.x >> 5);           // heavy tiles dispatched first
    const int nk = qt + 1;
    const size_t kbase = (size_t)bh * 2048 * 64;
    const u16* Vt = VTg + (size_t)bh * 64 * 2048;

    const int qrow = qt * 64 + wave * 16;
    bf16x8 qf[2];
    for (int c = 0; c < 2; c++)
        qf[c] = *(const bf16x8*)&Qp[kbase + (size_t)(qrow + l16) * 64 + c * 32 + quad * 8];

    f32x4 o[4] = {};
    float lsum = 0.f;
    const int qg = qrow + l16;                       // this lane's q (column of S^T)
    const int toff = (quad << 2);                    // t offset within 16-tile

    const int srow = tid >> 2, sc8 = (tid & 3) * 8;
#define ISSUE(k0v, b) do {                                                      \
        ASYNC16(&Kp[kbase + (size_t)((k0v) + srow) * 64 + sc8],      &Ks[b][0][srow][sc8]); \
        ASYNC16(&Kp[kbase + (size_t)((k0v) + srow) * 64 + 32 + sc8], &Ks[b][1][srow][sc8]); \
        ASYNC16(&Vt[(size_t)srow * 2048 + (k0v) + sc8],              &Vs[b][0][srow][sc8]); \
        ASYNC16(&Vt[(size_t)srow * 2048 + (k0v) + 32 + sc8],         &Vs[b][1][srow][sc8]); \
    } while (0)

    ISSUE(0, 0);
    for (int g = 0; g < nk; g++) {
        __syncthreads();   // drains DMA issued at g-1; guards buffer reuse
        if (g + 1 < nk) ISSUE((g + 1) * 64, (g + 1) & 1);
        const int cur = g & 1;
        const int k0 = g * 64;
        const bool diag = (g == nk - 1);

        f32x4 st[4];
        for (int kt = 0; kt < 4; kt++) {
            f32x4 a = {0.f, 0.f, 0.f, 0.f};
            // A = K rows (m = t), B = Q^T (n = q): same frags, swapped operands
            a = __builtin_amdgcn_mfma_f32_16x16x32_bf16(
                    *(const bf16x8*)&Ks[cur][0][kt * 16 + l16][quad * 8], qf[0], a, 0, 0, 0);
            a = __builtin_amdgcn_mfma_f32_16x16x32_bf16(
                    *(const bf16x8*)&Ks[cur][1][kt * 16 + l16][quad * 8], qf[1], a, 0, 0, 0);
            st[kt] = a;
        }
        for (int kt = 0; kt < 4; kt++) {
            h4 pa;
            if (diag) {
                for (int r = 0; r < 4; r++) {
                    int tg = k0 + kt * 16 + toff + r;
                    float p = (tg <= qg) ? __builtin_amdgcn_exp2f(st[kt][r]) : 0.f;
                    lsum += p;
                    pa[r] = (_Float16)p;
                }
            } else {
                for (int r = 0; r < 4; r++) {
                    float p = __builtin_amdgcn_exp2f(st[kt][r]);
                    lsum += p;
                    pa[r] = (_Float16)p;
                }
            }
            const int vp = kt >> 1, vo = (kt & 1) * 16 + toff;
            for (int dc = 0; dc < 4; dc++) {
                h4 vb = *(const h4*)&Vs[cur][vp][dc * 16 + l16][vo];
                o[dc] = __builtin_amdgcn_mfma_f32_16x16x16f16(pa, vb, o[dc], 0, 0, 0);
            }
        }
    }
#undef ISSUE

    // full row-sum for q = l16 (reduce partial t-chunks across quads)
    lsum += __shfl_xor(lsum, 16, 64);
    lsum += __shfl_xor(lsum, 32, 64);
    float rinv = 1.f / lsum;
    // broadcast: this lane outputs rows q = qrow + quad*4 + r, holds col d = l16
    float rq[4];
    for (int r = 0; r < 4; r++)
        rq[r] = __shfl(rinv, quad * 4 + r, 64);

    const int b = bh >> 4, h = bh & 15;
    for (int dc = 0; dc < 4; dc++)
        for (int r = 0; r < 4; r++) {
            int t = qrow + quad * 4 + r;
            Hb[((size_t)(b * 2048 + t)) * 1024 + h * 64 + dc * 16 + l16] = f2bf(o[dc][r] * rq[r]);
        }
}

// ---------------- layernorm (row = block), optional bf16 copy ----------------
__global__ __launch_bounds__(256) void ln_kernel(
    float* __restrict__ y, const float* __restrict__ g, const float* __restrict__ be,
    u16* __restrict__ bf_out)
{
    __shared__ float red[8];
    const int row = blockIdx.x, tid = threadIdx.x;
    float4 v = *(const float4*)&y[(size_t)row * 1024 + tid * 4];
    float sum = v.x + v.y + v.z + v.w;
    float sq  = v.x * v.x + v.y * v.y + v.z * v.z + v.w * v.w;
    for (int off = 1; off < 64; off <<= 1) {
        sum += __shfl_xor(sum, off, 64);
        sq  += __shfl_xor(sq,  off, 64);
    }
    int wave = tid >> 6;
    if ((tid & 63) == 0) { red[wave * 2] = sum; red[wave * 2 + 1] = sq; }
    __syncthreads();
    sum = red[0] + red[2] + red[4] + red[6];
    sq  = red[1] + red[3] + red[5] + red[7];
    float mu = sum * (1.f / 1024.f);
    float var = sq * (1.f / 1024.f) - mu * mu;
    float rstd = rsqrtf(var + 1e-5f);
    float4 gv = *(const float4*)&g[tid * 4];
    float4 bv = *(const float4*)&be[tid * 4];
    float4 ov;
    ov.x = (v.x - mu) * rstd * gv.x + bv.x;
    ov.y = (v.y - mu) * rstd * gv.y + bv.y;
    ov.z = (v.z - mu) * rstd * gv.z + bv.z;
    ov.w = (v.w - mu) * rstd * gv.w + bv.w;
    *(float4*)&y[(size_t)row * 1024 + tid * 4] = ov;
    if (bf_out) {
        ushort4 ob;
        ob.x = f2bf(ov.x); ob.y = f2bf(ov.y); ob.z = f2bf(ov.z); ob.w = f2bf(ov.w);
        *(ushort4*)&bf_out[(size_t)row * 1024 + tid * 4] = ob;
    }
}

// ---------------- launch ----------------
extern "C" void kernel_launch(void* const* d_in, const int* in_sizes, int n_in,
                              void* d_out, int out_size, void* d_ws, size_t ws_size,
                              hipStream_t stream)
{
    const float* x     = (const float*)d_in[0];
    const float* Wqkv  = (const float*)d_in[1];
    const float* bqkv  = (const float*)d_in[2];
    const float* Wout  = (const float*)d_in[3];
    const float* bout  = (const float*)d_in[4];
    const float* g1    = (const float*)d_in[5];
    const float* be1   = (const float*)d_in[6];
    const float* Wff1  = (const float*)d_in[7];
    const float* bff1  = (const float*)d_in[8];
    const float* Wff2  = (const float*)d_in[9];
    const float* bff2  = (const float*)d_in[10];
    const float* g2    = (const float*)d_in[11];
    const float* be2   = (const float*)d_in[12];
    float* out = (float*)d_out;

    char* wsb = (char*)d_ws;
    u16* WqkvT = (u16*)(wsb + 0);                   //  6 MB [3072,1024]
    u16* WoutT = (u16*)(wsb + 6291456);             //  2 MB [1024,1024]
    u16* Wff1T = (u16*)(wsb + 8388608);             //  4 MB [2048,1024]
    u16* Wff2T = (u16*)(wsb + 12582912);            //  4 MB [1024,2048]
    u16* xb    = (u16*)(wsb + 16777216);            //  8 MB [4096,1024]; reused as VT
    u16* Qp    = (u16*)(wsb + 25165824);            //  8 MB [B,H,T,D] bf16
    u16* Kp    = (u16*)(wsb + 33554432);            //  8 MB bf16
    u16* Vp    = (u16*)(wsb + 41943040);            //  8 MB f16
    u16* Hb    = (u16*)(wsb + 50331648);            //  8 MB [4096,1024] bf16
    u16* x1b   = (u16*)(wsb + 58720256);            //  8 MB [4096,1024] bf16
    u16* ff1b  = (u16*)(wsb + 67108864);            // 16 MB [4096,2048] bf16
    float* y1  = (float*)(wsb + 83886080);          // 16 MB fp32 [4096,1024]
    u16* VTg   = xb;                                // V^T f16 [bh][d][t]

    dim3 tb(32, 8);
    hipLaunchKernelGGL(transpose_convert, dim3(96, 32), tb, 0, stream, Wqkv, WqkvT, 1024, 3072);
    hipLaunchKernelGGL(transpose_convert, dim3(32, 32), tb, 0, stream, Wout, WoutT, 1024, 1024);
    hipLaunchKernelGGL(transpose_convert, dim3(64, 32), tb, 0, stream, Wff1, Wff1T, 1024, 2048);
    hipLaunchKernelGGL(transpose_convert, dim3(32, 64), tb, 0, stream, Wff2, Wff2T, 2048, 1024);
    hipLaunchKernelGGL(convert_bf16, dim3(4096), dim3(256), 0, stream, x, xb);

    // QKV projection (Q pre-scaled; V stored f16)
    hipLaunchKernelGGL((gemm_kernel<0>), dim3(24, 32), dim3(256), 0, stream,
                       xb, WqkvT, bqkv, nullptr, nullptr, 4096, 3072, 1024, Qp, Kp, Vp);
    // V transpose (f16 bits passthrough; overwrites xb — dead now)
    hipLaunchKernelGGL(vtrans_kernel, dim3(32, 32), dim3(64, 8), 0, stream, Vp, VTg);
    // attention
    hipLaunchKernelGGL(attn_kernel, dim3(1024), dim3(256), 0, stream, Qp, Kp, VTg, Hb);
    // out projection + residual (x) -> y1 fp32
    hipLaunchKernelGGL(gemm64_kernel, dim3(8, 64), dim3(256), 0, stream,
                       Hb, WoutT, bout, y1, x, 4096, 1024, 1024);
    // LN1 in-place on y1, emit bf16 x1b
    hipLaunchKernelGGL(ln_kernel, dim3(4096), dim3(256), 0, stream, y1, g1, be1, x1b);
    // FF1 + relu -> ff1b bf16
    hipLaunchKernelGGL((gemm_kernel<2>), dim3(16, 32), dim3(256), 0, stream,
                       x1b, Wff1T, bff1, (void*)ff1b, nullptr, 4096, 2048, 1024,
                       (u16*)nullptr, (u16*)nullptr, (u16*)nullptr);
    // FF2 + residual (y1 = x1 fp32) -> d_out fp32
    hipLaunchKernelGGL(gemm64_kernel, dim3(8, 64), dim3(256), 0, stream,
                       ff1b, Wff2T, bff2, out, y1, 4096, 1024, 2048);
    // LN2 in-place on d_out
    hipLaunchKernelGGL(ln_kernel, dim3(4096), dim3(256), 0, stream, out, g2, be2, (u16*)nullptr);
}

// Round 8
// 299.225 us; speedup vs baseline: 1.1610x; 1.1610x over previous
//
#include <hip/hip_runtime.h>

typedef __bf16 bf16x8 __attribute__((ext_vector_type(8)));
typedef float f32x4 __attribute__((ext_vector_type(4)));
typedef unsigned short u16;

#define ASYNC16(gp, lp) __builtin_amdgcn_global_load_lds( \
    (__attribute__((address_space(1))) void*)(gp),        \
    (__attribute__((address_space(3))) void*)(lp), 16, 0, 0)

// ---------------- helpers ----------------
static __device__ __forceinline__ u16 f2bf(float f) {
    union { float f; unsigned u; } v; v.f = f;
    unsigned r = v.u + 0x7FFFu + ((v.u >> 16) & 1u);   // RNE
    return (u16)(r >> 16);
}

#define QSCALE 0.18033688011112042f  /* 0.125 * log2(e) */

// ---------------- convert / transpose ----------------
__global__ void transpose_convert(const float* __restrict__ in, u16* __restrict__ out,
                                  int K, int N) {
    __shared__ float tile[32][33];
    int n0 = blockIdx.x * 32, k0 = blockIdx.y * 32;
    int tx = threadIdx.x, ty = threadIdx.y;
    for (int i = 0; i < 4; i++)
        tile[ty + 8 * i][tx] = in[(size_t)(k0 + ty + 8 * i) * N + n0 + tx];
    __syncthreads();
    for (int i = 0; i < 4; i++)
        out[(size_t)(n0 + ty + 8 * i) * K + k0 + tx] = f2bf(tile[tx][ty + 8 * i]);
}

__global__ void convert_bf16(const float* __restrict__ in, u16* __restrict__ out) {
    size_t i = ((size_t)blockIdx.x * 256 + threadIdx.x) * 4;
    float4 v = *(const float4*)&in[i];
    u16 o0 = f2bf(v.x), o1 = f2bf(v.y), o2 = f2bf(v.z), o3 = f2bf(v.w);
    ushort4 o; o.x = o0; o.y = o1; o.z = o2; o.w = o3;
    *(ushort4*)&out[i] = o;
}

// V [bh][t][d] -> VT [bh][d][t]   grid(32, 32) block(64,8)
__global__ void vtrans_kernel(const u16* __restrict__ Vp, u16* __restrict__ VT) {
    __shared__ u16 tile[64 * 66];
    const int bh = blockIdx.y, t0 = blockIdx.x * 64;
    const int tx = threadIdx.x, ty = threadIdx.y;
    const u16* src = Vp + (size_t)bh * 2048 * 64;
    u16* dst = VT + (size_t)bh * 64 * 2048;
    for (int i = 0; i < 8; i++)
        tile[(ty + 8 * i) * 66 + tx] = src[(size_t)(t0 + ty + 8 * i) * 64 + tx];
    __syncthreads();
    for (int i = 0; i < 8; i++) {
        int d = ty + 8 * i;
        dst[(size_t)d * 2048 + t0 + tx] = tile[tx * 66 + d];
    }
}

// ---------------- GEMM 128x128, single-barrier double-buffered pipeline ----------
// EPI 0: scatter to Q/K/V [B,H,T,D] bf16 (N=3072); Q scaled by QSCALE
// EPI 1: fp32 out = acc + bias + resid[m*N+n]
// EPI 2: bf16 out = relu(acc + bias)
template <int EPI>
__global__ __launch_bounds__(256) void gemm_kernel(
    const u16* __restrict__ A, const u16* __restrict__ BT,
    const float* __restrict__ bias, void* __restrict__ out0,
    const float* __restrict__ resid, int M, int N, int K,
    u16* __restrict__ q_out, u16* __restrict__ k_out, u16* __restrict__ v_out)
{
    __shared__ __align__(16) u16 As[2][128 * 32];
    __shared__ __align__(16) u16 Bs[2][128 * 32];
    const int tid = threadIdx.x;
    const int wave = tid >> 6, lane = tid & 63;
    const int quad = lane >> 4, l16 = lane & 15;
    const int m0 = blockIdx.y * 128, n0 = blockIdx.x * 128;
    const int wm = (wave >> 1) * 64, wn = (wave & 1) * 64;
    const int sr = tid >> 2, sc = (tid & 3) * 8;

    f32x4 acc[4][4] = {};

#define GISSUE(k0v, bb) do {                                                         \
        ASYNC16(&A[(size_t)(m0 + sr) * K + (k0v) + sc],       &As[bb][sr * 32 + sc]);        \
        ASYNC16(&A[(size_t)(m0 + sr + 64) * K + (k0v) + sc],  &As[bb][(sr + 64) * 32 + sc]); \
        ASYNC16(&BT[(size_t)(n0 + sr) * K + (k0v) + sc],      &Bs[bb][sr * 32 + sc]);        \
        ASYNC16(&BT[(size_t)(n0 + sr + 64) * K + (k0v) + sc], &Bs[bb][(sr + 64) * 32 + sc]); \
    } while (0)

    const int nk = K >> 5;
    GISSUE(0, 0);
    for (int it = 0; it < nk; it++) {
        __syncthreads();
        if (it + 1 < nk) GISSUE((it + 1) * 32, (it + 1) & 1);
        const u16* Ab = As[it & 1];
        const u16* Bb = Bs[it & 1];
        bf16x8 af[4], bfr[4];
        for (int i = 0; i < 4; i++) {
            af[i]  = *(const bf16x8*)&Ab[(wm + i * 16 + l16) * 32 + quad * 8];
            bfr[i] = *(const bf16x8*)&Bb[(wn + i * 16 + l16) * 32 + quad * 8];
        }
        for (int i = 0; i < 4; i++)
            for (int j = 0; j < 4; j++)
                acc[i][j] = __builtin_amdgcn_mfma_f32_16x16x32_bf16(af[i], bfr[j], acc[i][j], 0, 0, 0);
    }
#undef GISSUE

    for (int i = 0; i < 4; i++) {
        int mbase = m0 + wm + i * 16 + quad * 4;
        for (int j = 0; j < 4; j++) {
            int n = n0 + wn + j * 16 + l16;
            float bv = bias[n];
            for (int r = 0; r < 4; r++) {
                int m = mbase + r;
                float v = acc[i][j][r] + bv;
                if (EPI == 0) {
                    int s = n >> 10, rr = n & 1023, h = rr >> 6, d = rr & 63;
                    int b = m >> 11, t = m & 2047;
                    if (s == 0) v *= QSCALE;
                    u16* dst = (s == 0) ? q_out : (s == 1) ? k_out : v_out;
                    dst[((size_t)((b * 16 + h) * 2048 + t)) * 64 + d] = f2bf(v);
                } else if (EPI == 1) {
                    ((float*)out0)[(size_t)m * N + n] = v + resid[(size_t)m * N + n];
                } else {
                    ((u16*)out0)[(size_t)m * N + n] = f2bf(fmaxf(v, 0.f));
                }
            }
        }
    }
}

// ---------------- GEMM 64x128 (N=1024 GEMMs: 512 blocks => 2/CU) -----------
__global__ __launch_bounds__(256) void gemm64_kernel(
    const u16* __restrict__ A, const u16* __restrict__ BT,
    const float* __restrict__ bias, float* __restrict__ out0,
    const float* __restrict__ resid, int M, int N, int K)
{
    __shared__ __align__(16) u16 As[2][64 * 32];
    __shared__ __align__(16) u16 Bs[2][128 * 32];
    const int tid = threadIdx.x;
    const int wave = tid >> 6, lane = tid & 63;
    const int quad = lane >> 4, l16 = lane & 15;
    const int m0 = blockIdx.y * 64, n0 = blockIdx.x * 128;
    const int wn = wave * 32;
    const int sr = tid >> 2, sc = (tid & 3) * 8;

    f32x4 acc[4][2] = {};

#define GISSUE(k0v, bb) do {                                                         \
        ASYNC16(&A[(size_t)(m0 + sr) * K + (k0v) + sc],       &As[bb][sr * 32 + sc]);        \
        ASYNC16(&BT[(size_t)(n0 + sr) * K + (k0v) + sc],      &Bs[bb][sr * 32 + sc]);        \
        ASYNC16(&BT[(size_t)(n0 + sr + 64) * K + (k0v) + sc], &Bs[bb][(sr + 64) * 32 + sc]); \
    } while (0)

    const int nk = K >> 5;
    GISSUE(0, 0);
    for (int it = 0; it < nk; it++) {
        __syncthreads();
        if (it + 1 < nk) GISSUE((it + 1) * 32, (it + 1) & 1);
        const u16* Ab = As[it & 1];
        const u16* Bb = Bs[it & 1];
        bf16x8 af[4], bfr[2];
        for (int i = 0; i < 4; i++)
            af[i] = *(const bf16x8*)&Ab[(i * 16 + l16) * 32 + quad * 8];
        for (int j = 0; j < 2; j++)
            bfr[j] = *(const bf16x8*)&Bb[(wn + j * 16 + l16) * 32 + quad * 8];
        for (int i = 0; i < 4; i++)
            for (int j = 0; j < 2; j++)
                acc[i][j] = __builtin_amdgcn_mfma_f32_16x16x32_bf16(af[i], bfr[j], acc[i][j], 0, 0, 0);
    }
#undef GISSUE

    for (int i = 0; i < 4; i++) {
        int mbase = m0 + i * 16 + quad * 4;
        for (int j = 0; j < 2; j++) {
            int n = n0 + wn + j * 16 + l16;
            float bv = bias[n];
            for (int r = 0; r < 4; r++) {
                int m = mbase + r;
                out0[(size_t)m * N + n] = acc[i][j][r] + bv + resid[(size_t)m * N + n];
            }
        }
    }
}

// ---------------- flash attention v7: v5 inner loop, 1024-block grid ----------
// Proven v5 inner loop (S=Q*K^T, P via padded LDS, bf16 b128 V-frags) with a
// single 64-row Q-tile per block, heavy tiles dispatched first. LDS 41 KB ->
// 3 blocks/CU co-resident (vs 2 at grid 512): +50% TLP hides the P round-trip.
__device__ __forceinline__ void attn_step(
    const u16 (*Ksb)[64][32], const u16 (*Vsb)[64][32], u16* __restrict__ Pw,
    int k0, int qg, int l16, int quad, bool diag,
    const bf16x8 (&qf)[2], f32x4 (&o)[4], float (&lsum)[4])
{
    f32x4 s[4];
    for (int kt = 0; kt < 4; kt++) {
        f32x4 a = {0.f, 0.f, 0.f, 0.f};
        a = __builtin_amdgcn_mfma_f32_16x16x32_bf16(qf[0], *(const bf16x8*)&Ksb[0][kt * 16 + l16][quad * 8], a, 0, 0, 0);
        a = __builtin_amdgcn_mfma_f32_16x16x32_bf16(qf[1], *(const bf16x8*)&Ksb[1][kt * 16 + l16][quad * 8], a, 0, 0, 0);
        s[kt] = a;
    }
    if (diag) {
        for (int kt = 0; kt < 4; kt++) {
            const int kg = k0 + kt * 16 + l16;
            for (int r = 0; r < 4; r++) {
                float p = (kg <= qg + r) ? __builtin_amdgcn_exp2f(s[kt][r]) : 0.f;
                union { float f; unsigned u; } c; c.f = p;
                union { unsigned u; float f; } tf; tf.u = c.u & 0xFFFF0000u;
                lsum[r] += tf.f;
                Pw[(quad * 4 + r) * 72 + kt * 16 + l16] = (u16)(c.u >> 16);
            }
        }
    } else {
        for (int kt = 0; kt < 4; kt++)
            for (int r = 0; r < 4; r++) {
                float p = __builtin_amdgcn_exp2f(s[kt][r]);
                union { float f; unsigned u; } c; c.f = p;
                union { unsigned u; float f; } tf; tf.u = c.u & 0xFFFF0000u;
                lsum[r] += tf.f;
                Pw[(quad * 4 + r) * 72 + kt * 16 + l16] = (u16)(c.u >> 16);
            }
    }
    bf16x8 pa0 = *(const bf16x8*)&Pw[l16 * 72 + quad * 8];
    bf16x8 pa1 = *(const bf16x8*)&Pw[l16 * 72 + 32 + quad * 8];
    for (int dc = 0; dc < 4; dc++) {
        bf16x8 v0 = *(const bf16x8*)&Vsb[0][dc * 16 + l16][quad * 8];
        bf16x8 v1 = *(const bf16x8*)&Vsb[1][dc * 16 + l16][quad * 8];
        o[dc] = __builtin_amdgcn_mfma_f32_16x16x32_bf16(pa0, v0, o[dc], 0, 0, 0);
        o[dc] = __builtin_amdgcn_mfma_f32_16x16x32_bf16(pa1, v1, o[dc], 0, 0, 0);
    }
}

__global__ __launch_bounds__(256) void attn_kernel(
    const u16* __restrict__ Qp, const u16* __restrict__ Kp,
    const u16* __restrict__ VTg, u16* __restrict__ Hb)
{
    __shared__ __align__(16) u16 Ks[2][2][64][32];
    __shared__ __align__(16) u16 Vs[2][2][64][32];
    __shared__ __align__(16) u16 Pl[4][16][72];
    const int tid = threadIdx.x;
    const int wave = tid >> 6, lane = tid & 63;
    const int quad = lane >> 4, l16 = lane & 15;
    const int bh = ((blockIdx.x & 7) << 2) | ((blockIdx.x >> 3) & 3);
    const int qt = 31 - (blockIdx.x >> 5);           // heavy tiles first
    const int nk = qt + 1;
    const size_t kbase = (size_t)bh * 2048 * 64;
    const u16* Vt = VTg + (size_t)bh * 64 * 2048;
    u16* Pw = &Pl[wave][0][0];

    const int qrow = qt * 64 + wave * 16;
    bf16x8 qf[2];
    for (int c = 0; c < 2; c++)
        qf[c] = *(const bf16x8*)&Qp[kbase + (size_t)(qrow + l16) * 64 + c * 32 + quad * 8];

    f32x4 o[4] = {};
    float ls[4] = {0.f, 0.f, 0.f, 0.f};
    const int qg = qrow + quad * 4;

    const int srow = tid >> 2, sc8 = (tid & 3) * 8;
#define ISSUE(k0v, b) do {                                                      \
        ASYNC16(&Kp[kbase + (size_t)((k0v) + srow) * 64 + sc8],      &Ks[b][0][srow][sc8]); \
        ASYNC16(&Kp[kbase + (size_t)((k0v) + srow) * 64 + 32 + sc8], &Ks[b][1][srow][sc8]); \
        ASYNC16(&Vt[(size_t)srow * 2048 + (k0v) + sc8],              &Vs[b][0][srow][sc8]); \
        ASYNC16(&Vt[(size_t)srow * 2048 + (k0v) + 32 + sc8],         &Vs[b][1][srow][sc8]); \
    } while (0)

    ISSUE(0, 0);
    for (int g = 0; g < nk; g++) {
        __syncthreads();   // drains DMA issued at g-1; guards buffer reuse
        if (g + 1 < nk) ISSUE((g + 1) * 64, (g + 1) & 1);
        const int cur = g & 1;
        attn_step(Ks[cur], Vs[cur], Pw, g * 64, qg, l16, quad, g == nk - 1, qf, o, ls);
    }
#undef ISSUE

    float rl[4];
    for (int r = 0; r < 4; r++) {
        float t = ls[r];
        t += __shfl_xor(t, 1, 64);
        t += __shfl_xor(t, 2, 64);
        t += __shfl_xor(t, 4, 64);
        t += __shfl_xor(t, 8, 64);
        rl[r] = 1.f / t;
    }
    const int b = bh >> 4, h = bh & 15;
    for (int dc = 0; dc < 4; dc++)
        for (int r = 0; r < 4; r++) {
            int t = qrow + quad * 4 + r;
            Hb[((size_t)(b * 2048 + t)) * 1024 + h * 64 + dc * 16 + l16] = f2bf(o[dc][r] * rl[r]);
        }
}

// ---------------- layernorm (row = block), optional bf16 copy ----------------
__global__ __launch_bounds__(256) void ln_kernel(
    float* __restrict__ y, const float* __restrict__ g, const float* __restrict__ be,
    u16* __restrict__ bf_out)
{
    __shared__ float red[8];
    const int row = blockIdx.x, tid = threadIdx.x;
    float4 v = *(const float4*)&y[(size_t)row * 1024 + tid * 4];
    float sum = v.x + v.y + v.z + v.w;
    float sq  = v.x * v.x + v.y * v.y + v.z * v.z + v.w * v.w;
    for (int off = 1; off < 64; off <<= 1) {
        sum += __shfl_xor(sum, off, 64);
        sq  += __shfl_xor(sq,  off, 64);
    }
    int wave = tid >> 6;
    if ((tid & 63) == 0) { red[wave * 2] = sum; red[wave * 2 + 1] = sq; }
    __syncthreads();
    sum = red[0] + red[2] + red[4] + red[6];
    sq  = red[1] + red[3] + red[5] + red[7];
    float mu = sum * (1.f / 1024.f);
    float var = sq * (1.f / 1024.f) - mu * mu;
    float rstd = rsqrtf(var + 1e-5f);
    float4 gv = *(const float4*)&g[tid * 4];
    float4 bv = *(const float4*)&be[tid * 4];
    float4 ov;
    ov.x = (v.x - mu) * rstd * gv.x + bv.x;
    ov.y = (v.y - mu) * rstd * gv.y + bv.y;
    ov.z = (v.z - mu) * rstd * gv.z + bv.z;
    ov.w = (v.w - mu) * rstd * gv.w + bv.w;
    *(float4*)&y[(size_t)row * 1024 + tid * 4] = ov;
    if (bf_out) {
        ushort4 ob;
        ob.x = f2bf(ov.x); ob.y = f2bf(ov.y); ob.z = f2bf(ov.z); ob.w = f2bf(ov.w);
        *(ushort4*)&bf_out[(size_t)row * 1024 + tid * 4] = ob;
    }
}

// ---------------- launch ----------------
extern "C" void kernel_launch(void* const* d_in, const int* in_sizes, int n_in,
                              void* d_out, int out_size, void* d_ws, size_t ws_size,
                              hipStream_t stream)
{
    const float* x     = (const float*)d_in[0];
    const float* Wqkv  = (const float*)d_in[1];
    const float* bqkv  = (const float*)d_in[2];
    const float* Wout  = (const float*)d_in[3];
    const float* bout  = (const float*)d_in[4];
    const float* g1    = (const float*)d_in[5];
    const float* be1   = (const float*)d_in[6];
    const float* Wff1  = (const float*)d_in[7];
    const float* bff1  = (const float*)d_in[8];
    const float* Wff2  = (const float*)d_in[9];
    const float* bff2  = (const float*)d_in[10];
    const float* g2    = (const float*)d_in[11];
    const float* be2   = (const float*)d_in[12];
    float* out = (float*)d_out;

    char* wsb = (char*)d_ws;
    u16* WqkvT = (u16*)(wsb + 0);                   //  6 MB [3072,1024]
    u16* WoutT = (u16*)(wsb + 6291456);             //  2 MB [1024,1024]
    u16* Wff1T = (u16*)(wsb + 8388608);             //  4 MB [2048,1024]
    u16* Wff2T = (u16*)(wsb + 12582912);            //  4 MB [1024,2048]
    u16* xb    = (u16*)(wsb + 16777216);            //  8 MB [4096,1024]; reused as VT
    u16* Qp    = (u16*)(wsb + 25165824);            //  8 MB [B,H,T,D] bf16
    u16* Kp    = (u16*)(wsb + 33554432);            //  8 MB bf16
    u16* Vp    = (u16*)(wsb + 41943040);            //  8 MB bf16
    u16* Hb    = (u16*)(wsb + 50331648);            //  8 MB [4096,1024] bf16
    u16* x1b   = (u16*)(wsb + 58720256);            //  8 MB [4096,1024] bf16
    u16* ff1b  = (u16*)(wsb + 67108864);            // 16 MB [4096,2048] bf16
    float* y1  = (float*)(wsb + 83886080);          // 16 MB fp32 [4096,1024]
    u16* VTg   = xb;                                // V^T bf16 [bh][d][t]

    dim3 tb(32, 8);
    hipLaunchKernelGGL(transpose_convert, dim3(96, 32), tb, 0, stream, Wqkv, WqkvT, 1024, 3072);
    hipLaunchKernelGGL(transpose_convert, dim3(32, 32), tb, 0, stream, Wout, WoutT, 1024, 1024);
    hipLaunchKernelGGL(transpose_convert, dim3(64, 32), tb, 0, stream, Wff1, Wff1T, 1024, 2048);
    hipLaunchKernelGGL(transpose_convert, dim3(32, 64), tb, 0, stream, Wff2, Wff2T, 2048, 1024);
    hipLaunchKernelGGL(convert_bf16, dim3(4096), dim3(256), 0, stream, x, xb);

    // QKV projection (Q pre-scaled by 0.125*log2e)
    hipLaunchKernelGGL((gemm_kernel<0>), dim3(24, 32), dim3(256), 0, stream,
                       xb, WqkvT, bqkv, nullptr, nullptr, 4096, 3072, 1024, Qp, Kp, Vp);
    // V transpose (overwrites xb — dead now)
    hipLaunchKernelGGL(vtrans_kernel, dim3(32, 32), dim3(64, 8), 0, stream, Vp, VTg);
    // attention
    hipLaunchKernelGGL(attn_kernel, dim3(1024), dim3(256), 0, stream, Qp, Kp, VTg, Hb);
    // out projection + residual (x) -> y1 fp32
    hipLaunchKernelGGL(gemm64_kernel, dim3(8, 64), dim3(256), 0, stream,
                       Hb, WoutT, bout, y1, x, 4096, 1024, 1024);
    // LN1 in-place on y1, emit bf16 x1b
    hipLaunchKernelGGL(ln_kernel, dim3(4096), dim3(256), 0, stream, y1, g1, be1, x1b);
    // FF1 + relu -> ff1b bf16
    hipLaunchKernelGGL((gemm_kernel<2>), dim3(16, 32), dim3(256), 0, stream,
                       x1b, Wff1T, bff1, (void*)ff1b, nullptr, 4096, 2048, 1024,
                       (u16*)nullptr, (u16*)nullptr, (u16*)nullptr);
    // FF2 + residual (y1 = x1 fp32) -> d_out fp32
    hipLaunchKernelGGL(gemm64_kernel, dim3(8, 64), dim3(256), 0, stream,
                       ff1b, Wff2T, bff2, out, y1, 4096, 1024, 2048);
    // LN2 in-place on d_out
    hipLaunchKernelGGL(ln_kernel, dim3(4096), dim3(256), 0, stream, out, g2, be2, (u16*)nullptr);
}